// Round 5
// baseline (705.719 us; speedup 1.0000x reference)
//
#include <hip/hip_runtime.h>

// GCN layer: out = D^-1/2 (A + I) D^-1/2 (x @ kernel) + bias
// N=100000, E=1600000, F=U=64, fp32 in/out; h2 staged as bf16.
// Pipeline: bucket counting-sort (bucket = 64 dest nodes), per-bucket
// edge-parallel pull with LDS f32 tile accumulation (no per-node sort).

typedef unsigned long long u64;
#define FILL 1.0f
#define SB 6
#define BKN 64                    // nodes per bucket
#define EPT 16                    // edges/thread per scatter tile (tile = 4096)

__device__ inline unsigned bf16rne(float f) {
    unsigned u = __float_as_uint(f);
    return (u + 0x7FFFu + ((u >> 16) & 1u)) >> 16;
}
__device__ inline unsigned pack2(float lo, float hi) {
    return bf16rne(lo) | (bf16rne(hi) << 16);
}
__device__ inline float unlo(unsigned g) { return __uint_as_float(g << 16); }
__device__ inline float unhi(unsigned g) { return __uint_as_float(g & 0xFFFF0000u); }

// ---------------- phase 1: bucket histogram + scan ----------------

__global__ __launch_bounds__(256) void k_bhist(const int* __restrict__ row,
                                               int* __restrict__ bcnt, int E, int NB) {
    __shared__ int h[2048];
    for (int i = threadIdx.x; i < NB; i += 256) h[i] = 0;
    __syncthreads();
    int stride = gridDim.x * 256;
    for (int e = blockIdx.x * 256 + threadIdx.x; e < E; e += stride)
        atomicAdd(&h[row[e] >> SB], 1);
    __syncthreads();
    for (int i = threadIdx.x; i < NB; i += 256)
        if (h[i]) atomicAdd(&bcnt[i], h[i]);
}

// single-block scan of up to 2048 bucket counts
__global__ __launch_bounds__(1024) void k_bscan(const int* __restrict__ bcnt,
                                                int* __restrict__ bstart,
                                                int* __restrict__ bcur, int NB, int E) {
    __shared__ int a[2048], b[2048];
    int t = threadIdx.x;
    for (int p = t; p < 2048; p += 1024) a[p] = (p < NB) ? bcnt[p] : 0;
    __syncthreads();
    int *src = a, *dst = b;
    for (int o = 1; o < 2048; o <<= 1) {
        for (int p = t; p < 2048; p += 1024) {
            int v = src[p];
            if (p >= o) v += src[p - o];
            dst[p] = v;
        }
        __syncthreads();
        int* tm = src; src = dst; dst = tm;
    }
    for (int p = t; p < 2048; p += 1024) {
        if (p < NB) {
            int excl = src[p] - bcnt[p];
            bstart[p] = excl;
            bcur[p] = excl;
        }
    }
    if (t == 0) bstart[NB] = E;
}

// ---------------- phase 2: tile-reserved bucket scatter ----------------
// record: w(63..32) | row_local(29..24, 6 bits) | col(23..0)

__global__ __launch_bounds__(256) void k_bscatter(const int* __restrict__ row,
                                                  const int* __restrict__ col,
                                                  const float* __restrict__ w,
                                                  int* __restrict__ bcur,
                                                  u64* __restrict__ eA, int E, int NB) {
    __shared__ int cnt[2048];
    __shared__ int ofs[2048];
    int nt = (E + 4095) >> 12;
    for (int tile = blockIdx.x; tile < nt; tile += gridDim.x) {
        int base = tile << 12;
        for (int i = threadIdx.x; i < NB; i += 256) cnt[i] = 0;
        __syncthreads();
        int bk[EPT]; u64 rec[EPT];
        #pragma unroll
        for (int k = 0; k < EPT; ++k) {
            int e = base + threadIdx.x + (k << 8);
            bk[k] = -1;
            if (e < E) {
                int r = row[e];
                bk[k] = r >> SB;
                rec[k] = ((u64)__float_as_uint(w[e]) << 32)
                       | ((u64)(unsigned)(r & (BKN - 1)) << 24)
                       | (u64)(unsigned)col[e];
                atomicAdd(&cnt[bk[k]], 1);
            }
        }
        __syncthreads();
        for (int i = threadIdx.x; i < NB; i += 256) {
            int c = cnt[i];
            ofs[i] = c ? atomicAdd(&bcur[i], c) : 0;
            cnt[i] = 0;
        }
        __syncthreads();
        #pragma unroll
        for (int k = 0; k < EPT; ++k) {
            if (bk[k] >= 0) {
                int pos = ofs[bk[k]] + atomicAdd(&cnt[bk[k]], 1);
                eA[pos] = rec[k];
            }
        }
        __syncthreads();
    }
}

// ---------------- phase 3: per-bucket degree -> dis ----------------

__global__ __launch_bounds__(256) void k_deg(const int* __restrict__ bstart,
                                             const u64* __restrict__ eA,
                                             float* __restrict__ dis, int N) {
    __shared__ float degs[BKN];
    int b = blockIdx.x, t = threadIdx.x;
    if (t < BKN) degs[t] = 0.f;
    __syncthreads();
    int s = bstart[b], e1 = bstart[b + 1];
    for (int i = s + t; i < e1; i += 256) {
        u64 p = eA[i];
        int rl = (int)((p >> 24) & (BKN - 1));
        atomicAdd(&degs[rl], __uint_as_float((unsigned)(p >> 32)));
    }
    __syncthreads();
    int node = (b << SB) + t;
    if (t < BKN && node < N) {
        float d = FILL + degs[t];
        dis[node] = (d > 0.f) ? rsqrtf(fmaxf(d, 1e-12f)) : 0.f;
    }
}

// ---------------- h2b = bf16( dis[r] * (x @ kernel) ) ----------------
// word u of a row packs units (2u, 2u+1)

__global__ __launch_bounds__(256) void k_gemm(const float* __restrict__ x,
                                              const float* __restrict__ kern,
                                              const float* __restrict__ dis,
                                              unsigned* __restrict__ h2b, int n) {
    __shared__ __align__(16) float ks[64 * 64];
    __shared__ __align__(16) float xs[64 * 68];
    int t = threadIdx.x;

    const float4* k4g = (const float4*)kern;
    float4* ks4 = (float4*)ks;
    #pragma unroll
    for (int i = 0; i < 4; ++i) ks4[t + i * 256] = k4g[t + i * 256];

    int r0 = blockIdx.x * 64;
    #pragma unroll
    for (int i = 0; i < 4; ++i) {
        int idx = t + i * 256;
        int rr = idx >> 4;
        int c4 = (idx & 15) << 2;
        int gr = r0 + rr;
        float4 v = make_float4(0.f, 0.f, 0.f, 0.f);
        if (gr < n) v = *(const float4*)(x + (size_t)gr * 64 + c4);
        *(float4*)(xs + rr * 68 + c4) = v;
    }
    __syncthreads();

    int rg = t >> 4;
    int ug = t & 15;
    float4 acc[4];
    #pragma unroll
    for (int r = 0; r < 4; ++r) acc[r] = make_float4(0.f, 0.f, 0.f, 0.f);

    #pragma unroll 2
    for (int kk = 0; kk < 16; ++kk) {
        float4 wv0 = *(const float4*)(ks + (kk * 4 + 0) * 64 + ug * 4);
        float4 wv1 = *(const float4*)(ks + (kk * 4 + 1) * 64 + ug * 4);
        float4 wv2 = *(const float4*)(ks + (kk * 4 + 2) * 64 + ug * 4);
        float4 wv3 = *(const float4*)(ks + (kk * 4 + 3) * 64 + ug * 4);
        #pragma unroll
        for (int r = 0; r < 4; ++r) {
            float4 xv = *(const float4*)(xs + (rg * 4 + r) * 68 + kk * 4);
            acc[r].x = fmaf(xv.x, wv0.x, acc[r].x);
            acc[r].y = fmaf(xv.x, wv0.y, acc[r].y);
            acc[r].z = fmaf(xv.x, wv0.z, acc[r].z);
            acc[r].w = fmaf(xv.x, wv0.w, acc[r].w);
            acc[r].x = fmaf(xv.y, wv1.x, acc[r].x);
            acc[r].y = fmaf(xv.y, wv1.y, acc[r].y);
            acc[r].z = fmaf(xv.y, wv1.z, acc[r].z);
            acc[r].w = fmaf(xv.y, wv1.w, acc[r].w);
            acc[r].x = fmaf(xv.z, wv2.x, acc[r].x);
            acc[r].y = fmaf(xv.z, wv2.y, acc[r].y);
            acc[r].z = fmaf(xv.z, wv2.z, acc[r].z);
            acc[r].w = fmaf(xv.z, wv2.w, acc[r].w);
            acc[r].x = fmaf(xv.w, wv3.x, acc[r].x);
            acc[r].y = fmaf(xv.w, wv3.y, acc[r].y);
            acc[r].z = fmaf(xv.w, wv3.z, acc[r].z);
            acc[r].w = fmaf(xv.w, wv3.w, acc[r].w);
        }
    }

    #pragma unroll
    for (int r = 0; r < 4; ++r) {
        int gr = r0 + rg * 4 + r;
        if (gr < n) {
            float d = dis[gr];
            uint2 uu;
            uu.x = pack2(d * acc[r].x, d * acc[r].y);
            uu.y = pack2(d * acc[r].z, d * acc[r].w);
            *(uint2*)(h2b + (size_t)gr * 32 + ug * 2) = uu;
        }
    }
}

// ---------------- phase 4: per-bucket edge-parallel pull ----------------

__global__ __launch_bounds__(256) void k_pull(const int* __restrict__ bstart,
                                              const u64* __restrict__ eA,
                                              const unsigned* __restrict__ h2b,
                                              const float* __restrict__ dis,
                                              const float* __restrict__ bias,
                                              float* __restrict__ out, int N) {
    __shared__ float tile[BKN * 64];        // 16 KB
    int b = blockIdx.x, t = threadIdx.x;
    {
        float4* t4 = (float4*)tile;
        #pragma unroll
        for (int i = t; i < BKN * 16; i += 256) t4[i] = make_float4(0.f, 0.f, 0.f, 0.f);
    }
    __syncthreads();
    int s = bstart[b], e1 = bstart[b + 1];
    int slot = t >> 5;          // 0..7
    int lane = t & 31;          // bf16-pair word
    for (int base = s; base < e1; base += 32) {
        #pragma unroll
        for (int k = 0; k < 4; ++k) {
            int idx = base + slot + k * 8;
            if (idx < e1) {
                u64 p = eA[idx];
                int c  = (int)((unsigned)p & 0xFFFFFF);
                int rl = (int)((p >> 24) & (BKN - 1));
                float v = __uint_as_float((unsigned)(p >> 32));
                unsigned g = h2b[((unsigned)c << 5) + lane];
                atomicAdd(&tile[(rl << 6) + 2 * lane],     v * unlo(g));
                atomicAdd(&tile[(rl << 6) + 2 * lane + 1], v * unhi(g));
            }
        }
    }
    __syncthreads();
    int node0 = b << SB;
    for (int idx = t; idx < BKN * 64; idx += 256) {
        int rl = idx >> 6, u = idx & 63;
        int node = node0 + rl;
        if (node < N) {
            float di = dis[node];
            unsigned gs = h2b[((unsigned)node << 5) + (u >> 1)];
            float hv = (u & 1) ? unhi(gs) : unlo(gs);
            out[((size_t)node << 6) + u] = di * tile[idx] + FILL * di * hv + bias[u];
        }
    }
}

// ---------------- fallback (atomic scatter) ----------------

__global__ void k_fb_deg_init(float* __restrict__ deg, int n) {
    int i = blockIdx.x * blockDim.x + threadIdx.x;
    if (i < n) deg[i] = FILL;
}
__global__ void k_fb_deg_edges(const int* __restrict__ row, const float* __restrict__ w,
                               float* __restrict__ deg, int E) {
    int e = blockIdx.x * blockDim.x + threadIdx.x;
    if (e < E) atomicAdd(&deg[row[e]], w[e]);
}
__global__ void k_fb_dis(const float* __restrict__ deg, float* __restrict__ dis, int n) {
    int i = blockIdx.x * blockDim.x + threadIdx.x;
    if (i < n) {
        float d = deg[i];
        dis[i] = (d > 0.f) ? rsqrtf(fmaxf(d, 1e-12f)) : 0.f;
    }
}
__global__ void k_fb_outinit(const unsigned* __restrict__ h2b, const float* __restrict__ dis,
                             const float* __restrict__ bias, float* __restrict__ out, int n) {
    int t = blockIdx.x * blockDim.x + threadIdx.x;
    if (t < n * 64) {
        int i = t >> 6, u = t & 63;
        unsigned g = h2b[(size_t)i * 32 + (u >> 1)];
        float hv = (u & 1) ? unhi(g) : unlo(g);
        out[t] = FILL * dis[i] * hv + bias[u];
    }
}
__global__ __launch_bounds__(256) void k_fb_scatter(const int* __restrict__ row,
                                                    const int* __restrict__ col,
                                                    const float* __restrict__ w,
                                                    const float* __restrict__ dis,
                                                    const unsigned* __restrict__ h2b,
                                                    float* __restrict__ out, int E) {
    long long t = (long long)blockIdx.x * blockDim.x + threadIdx.x;
    int e = (int)(t >> 4);
    int j = (int)(t & 15);
    if (e < E) {
        int r = row[e], c = col[e];
        float nw = dis[r] * w[e];
        uint2 g2 = *(const uint2*)(h2b + (size_t)c * 32 + 2 * j);
        float* op = out + (long long)r * 64 + j * 4;
        atomicAdd(op + 0, unlo(g2.x) * nw);
        atomicAdd(op + 1, unhi(g2.x) * nw);
        atomicAdd(op + 2, unlo(g2.y) * nw);
        atomicAdd(op + 3, unhi(g2.y) * nw);
    }
}

// ---------------- launch ----------------

extern "C" void kernel_launch(void* const* d_in, const int* in_sizes, int n_in,
                              void* d_out, int out_size, void* d_ws, size_t ws_size,
                              hipStream_t stream) {
    const float* x    = (const float*)d_in[0];
    const int*   ei   = (const int*)d_in[1];
    const float* ew   = (const float*)d_in[2];
    const float* kern = (const float*)d_in[3];
    const float* bias = (const float*)d_in[4];
    float* out = (float*)d_out;

    int N = in_sizes[0] / 64;
    int E = in_sizes[1] / 2;
    const int* row = ei;
    const int* col = ei + E;

    const int B = 256;
    int NB = (N + BKN - 1) >> SB;

    size_t need = (size_t)E * 8               // eA
                + (size_t)N * 128             // h2b (bf16 pairs)
                + (size_t)N * 4               // dis
                + (size_t)(3 * NB + 1) * 4;   // bcnt, bstart[NB+1], bcur

    if (ws_size >= need && NB <= 2048 && N <= (1 << 24)) {
        char* p = (char*)d_ws;
        u64*      eA    = (u64*)p;         p += (size_t)E * 8;
        unsigned* h2b   = (unsigned*)p;    p += (size_t)N * 128;
        float*    dis   = (float*)p;       p += (size_t)N * 4;
        int*      bcnt  = (int*)p;         p += (size_t)NB * 4;
        int*      bstart= (int*)p;         p += (size_t)(NB + 1) * 4;
        int*      bcur  = (int*)p;

        int nt = (E + 4095) >> 12;
        hipMemsetAsync(bcnt, 0, (size_t)NB * 4, stream);
        k_bhist<<<1024, B, 0, stream>>>(row, bcnt, E, NB);
        k_bscan<<<1, 1024, 0, stream>>>(bcnt, bstart, bcur, NB, E);
        k_bscatter<<<nt, B, 0, stream>>>(row, col, ew, bcur, eA, E, NB);
        k_deg<<<NB, B, 0, stream>>>(bstart, eA, dis, N);
        k_gemm<<<(N + 63) / 64, B, 0, stream>>>(x, kern, dis, h2b, N);
        k_pull<<<NB, B, 0, stream>>>(bstart, eA, h2b, dis, bias, out, N);
    } else {
        char* p = (char*)d_ws;
        unsigned* h2b = (unsigned*)p;  p += (size_t)N * 128;
        float*    deg = (float*)p;     p += (size_t)N * 4;
        float*    dis = (float*)p;

        k_fb_deg_init<<<(N + B - 1) / B, B, 0, stream>>>(deg, N);
        k_fb_deg_edges<<<(E + B - 1) / B, B, 0, stream>>>(row, ew, deg, E);
        k_fb_dis<<<(N + B - 1) / B, B, 0, stream>>>(deg, dis, N);
        k_gemm<<<(N + 63) / 64, B, 0, stream>>>(x, kern, dis, h2b, N);
        k_fb_outinit<<<((long long)N * 64 + B - 1) / B, B, 0, stream>>>(h2b, dis, bias, out, N);
        long long st = (long long)E * 16;
        k_fb_scatter<<<(st + B - 1) / B, B, 0, stream>>>(row, col, ew, dis, h2b, out, E);
    }
}

// Round 6
// 205.155 us; speedup vs baseline: 3.4399x; 3.4399x over previous
//
#include <hip/hip_runtime.h>

// GCN layer: out = D^-1/2 (A + I) D^-1/2 (x @ kernel) + bias
// N=100000, E=1600000, F=U=64, fp32 in/out; h2 staged as bf16.
// Pipeline: bucket counting-sort by destination (bucket = 64 dest nodes),
// fused deg+GEMM, then per-bucket pull kernel that fine-sorts records in LDS
// (2 LDS atomics/edge) and runs wave-per-node atomic-free gather/accumulate.

typedef unsigned long long u64;
#define FILL 1.0f
#define SB 6
#define BKN 64                    // nodes per bucket == gemm tile rows
#define EPT 16                    // edges/thread per scatter tile (tile = 4096)
#define CAP 2048                  // max records sorted per LDS chunk

__device__ inline unsigned bf16rne(float f) {
    unsigned u = __float_as_uint(f);
    return (u + 0x7FFFu + ((u >> 16) & 1u)) >> 16;
}
__device__ inline unsigned pack2(float lo, float hi) {
    return bf16rne(lo) | (bf16rne(hi) << 16);
}
__device__ inline float unlo(unsigned g) { return __uint_as_float(g << 16); }
__device__ inline float unhi(unsigned g) { return __uint_as_float(g & 0xFFFF0000u); }

// ---------------- phase 1: bucket histogram + scan ----------------

__global__ __launch_bounds__(256) void k_bhist(const int* __restrict__ row,
                                               int* __restrict__ bcnt, int E, int NB) {
    __shared__ int h[2048];
    for (int i = threadIdx.x; i < NB; i += 256) h[i] = 0;
    __syncthreads();
    int stride = gridDim.x * 256;
    for (int e = blockIdx.x * 256 + threadIdx.x; e < E; e += stride)
        atomicAdd(&h[row[e] >> SB], 1);
    __syncthreads();
    for (int i = threadIdx.x; i < NB; i += 256)
        if (h[i]) atomicAdd(&bcnt[i], h[i]);
}

__global__ __launch_bounds__(1024) void k_bscan(const int* __restrict__ bcnt,
                                                int* __restrict__ bstart,
                                                int* __restrict__ bcur, int NB, int E) {
    __shared__ int a[2048], b[2048];
    int t = threadIdx.x;
    for (int p = t; p < 2048; p += 1024) a[p] = (p < NB) ? bcnt[p] : 0;
    __syncthreads();
    int *src = a, *dst = b;
    for (int o = 1; o < 2048; o <<= 1) {
        for (int p = t; p < 2048; p += 1024) {
            int v = src[p];
            if (p >= o) v += src[p - o];
            dst[p] = v;
        }
        __syncthreads();
        int* tm = src; src = dst; dst = tm;
    }
    for (int p = t; p < 2048; p += 1024) {
        if (p < NB) {
            int excl = src[p] - bcnt[p];
            bstart[p] = excl;
            bcur[p] = excl;
        }
    }
    if (t == 0) bstart[NB] = E;
}

// ---------------- phase 2: tile-reserved bucket scatter ----------------
// record: w(63..32) | row_local(29..24, 6 bits) | col(23..0)

__global__ __launch_bounds__(256) void k_bscatter(const int* __restrict__ row,
                                                  const int* __restrict__ col,
                                                  const float* __restrict__ w,
                                                  int* __restrict__ bcur,
                                                  u64* __restrict__ eA, int E, int NB) {
    __shared__ int cnt[2048];
    __shared__ int ofs[2048];
    int nt = (E + 4095) >> 12;
    for (int tile = blockIdx.x; tile < nt; tile += gridDim.x) {
        int base = tile << 12;
        for (int i = threadIdx.x; i < NB; i += 256) cnt[i] = 0;
        __syncthreads();
        int bk[EPT]; u64 rec[EPT];
        #pragma unroll
        for (int k = 0; k < EPT; ++k) {
            int e = base + threadIdx.x + (k << 8);
            bk[k] = -1;
            if (e < E) {
                int r = row[e];
                bk[k] = r >> SB;
                rec[k] = ((u64)__float_as_uint(w[e]) << 32)
                       | ((u64)(unsigned)(r & (BKN - 1)) << 24)
                       | (u64)(unsigned)col[e];
                atomicAdd(&cnt[bk[k]], 1);
            }
        }
        __syncthreads();
        for (int i = threadIdx.x; i < NB; i += 256) {
            int c = cnt[i];
            ofs[i] = c ? atomicAdd(&bcur[i], c) : 0;
            cnt[i] = 0;
        }
        __syncthreads();
        #pragma unroll
        for (int k = 0; k < EPT; ++k) {
            if (bk[k] >= 0) {
                int pos = ofs[bk[k]] + atomicAdd(&cnt[bk[k]], 1);
                eA[pos] = rec[k];
            }
        }
        __syncthreads();
    }
}

// ---------------- fused deg + h2b = bf16( dis[r] * (x @ kernel) ) ----------------
// block = 64 rows == one dest bucket. If bstart!=nullptr, compute deg->dis here.

__global__ __launch_bounds__(256) void k_gemm(const float* __restrict__ x,
                                              const float* __restrict__ kern,
                                              const int* __restrict__ bstart,
                                              const u64* __restrict__ eA,
                                              float* __restrict__ dis,
                                              unsigned* __restrict__ h2b, int n) {
    __shared__ __align__(16) float ks[64 * 64];
    __shared__ __align__(16) float xs[64 * 68];
    __shared__ float degs[64];
    int t = threadIdx.x;
    int b = blockIdx.x;
    int r0 = b << SB;

    // deg phase (or load precomputed dis in fallback mode)
    if (bstart) {
        if (t < 64) degs[t] = 0.f;
        __syncthreads();
        int s = bstart[b], e1 = bstart[b + 1];
        for (int i = s + t; i < e1; i += 256) {
            u64 p = eA[i];
            atomicAdd(&degs[(int)((p >> 24) & (BKN - 1))],
                      __uint_as_float((unsigned)(p >> 32)));
        }
        __syncthreads();
        if (t < 64) {
            int node = r0 + t;
            if (node < n) {
                float d = FILL + degs[t];
                float di = (d > 0.f) ? rsqrtf(fmaxf(d, 1e-12f)) : 0.f;
                degs[t] = di;
                dis[node] = di;
            }
        }
    } else {
        if (t < 64) {
            int node = r0 + t;
            degs[t] = (node < n) ? dis[node] : 0.f;
        }
    }

    const float4* k4g = (const float4*)kern;
    float4* ks4 = (float4*)ks;
    #pragma unroll
    for (int i = 0; i < 4; ++i) ks4[t + i * 256] = k4g[t + i * 256];

    #pragma unroll
    for (int i = 0; i < 4; ++i) {
        int idx = t + i * 256;
        int rr = idx >> 4;
        int c4 = (idx & 15) << 2;
        int gr = r0 + rr;
        float4 v = make_float4(0.f, 0.f, 0.f, 0.f);
        if (gr < n) v = *(const float4*)(x + (size_t)gr * 64 + c4);
        *(float4*)(xs + rr * 68 + c4) = v;
    }
    __syncthreads();

    int rg = t >> 4;
    int ug = t & 15;
    float4 acc[4];
    #pragma unroll
    for (int r = 0; r < 4; ++r) acc[r] = make_float4(0.f, 0.f, 0.f, 0.f);

    #pragma unroll 2
    for (int kk = 0; kk < 16; ++kk) {
        float4 wv0 = *(const float4*)(ks + (kk * 4 + 0) * 64 + ug * 4);
        float4 wv1 = *(const float4*)(ks + (kk * 4 + 1) * 64 + ug * 4);
        float4 wv2 = *(const float4*)(ks + (kk * 4 + 2) * 64 + ug * 4);
        float4 wv3 = *(const float4*)(ks + (kk * 4 + 3) * 64 + ug * 4);
        #pragma unroll
        for (int r = 0; r < 4; ++r) {
            float4 xv = *(const float4*)(xs + (rg * 4 + r) * 68 + kk * 4);
            acc[r].x = fmaf(xv.x, wv0.x, acc[r].x);
            acc[r].y = fmaf(xv.x, wv0.y, acc[r].y);
            acc[r].z = fmaf(xv.x, wv0.z, acc[r].z);
            acc[r].w = fmaf(xv.x, wv0.w, acc[r].w);
            acc[r].x = fmaf(xv.y, wv1.x, acc[r].x);
            acc[r].y = fmaf(xv.y, wv1.y, acc[r].y);
            acc[r].z = fmaf(xv.y, wv1.z, acc[r].z);
            acc[r].w = fmaf(xv.y, wv1.w, acc[r].w);
            acc[r].x = fmaf(xv.z, wv2.x, acc[r].x);
            acc[r].y = fmaf(xv.z, wv2.y, acc[r].y);
            acc[r].z = fmaf(xv.z, wv2.z, acc[r].z);
            acc[r].w = fmaf(xv.z, wv2.w, acc[r].w);
            acc[r].x = fmaf(xv.w, wv3.x, acc[r].x);
            acc[r].y = fmaf(xv.w, wv3.y, acc[r].y);
            acc[r].z = fmaf(xv.w, wv3.z, acc[r].z);
            acc[r].w = fmaf(xv.w, wv3.w, acc[r].w);
        }
    }

    #pragma unroll
    for (int r = 0; r < 4; ++r) {
        int rr = rg * 4 + r;
        int gr = r0 + rr;
        if (gr < n) {
            float d = degs[rr];
            uint2 uu;
            uu.x = pack2(d * acc[r].x, d * acc[r].y);
            uu.y = pack2(d * acc[r].z, d * acc[r].w);
            *(uint2*)(h2b + (size_t)gr * 32 + ug * 2) = uu;
        }
    }
}

// ---------------- phase 4: per-bucket pull (LDS fine sort + wave-per-node) ----

__global__ __launch_bounds__(256) void k_pull(const int* __restrict__ bstart,
                                              const u64* __restrict__ eA,
                                              const unsigned* __restrict__ h2b,
                                              const float* __restrict__ dis,
                                              const float* __restrict__ bias,
                                              float* __restrict__ out, int N) {
    __shared__ u64 rec2[CAP];          // sorted records, 16 KB
    __shared__ int cnt[BKN];
    __shared__ int seg[BKN + 1];
    __shared__ int cur[BKN];
    int b = blockIdx.x, t = threadIdx.x;
    int s = bstart[b], e1 = bstart[b + 1];
    int total = e1 - s;
    int wid = t >> 6, lane = t & 63;
    int eh = lane >> 5, up = lane & 31;

    float accA[16], accB[16];
    #pragma unroll
    for (int k = 0; k < 16; ++k) { accA[k] = 0.f; accB[k] = 0.f; }

    for (int cbase = 0; cbase < total; cbase += CAP) {
        int cn = min(CAP, total - cbase);
        __syncthreads();                    // prev chunk processing complete
        if (t < BKN) cnt[t] = 0;
        __syncthreads();
        for (int i = t; i < cn; i += 256)
            atomicAdd(&cnt[(int)((eA[s + cbase + i] >> 24) & (BKN - 1))], 1);
        __syncthreads();
        if (wid == 0) {
            int c0 = cnt[lane];
            int v = c0;
            #pragma unroll
            for (int o = 1; o < BKN; o <<= 1) {
                int u = __shfl_up(v, o);
                if (lane >= o) v += u;
            }
            seg[lane + 1] = v;
            cur[lane] = v - c0;
            if (lane == 0) seg[0] = 0;
        }
        __syncthreads();
        for (int i = t; i < cn; i += 256) {
            u64 p = eA[s + cbase + i];
            int rl = (int)((p >> 24) & (BKN - 1));
            int pos = atomicAdd(&cur[rl], 1);
            rec2[pos] = p;
        }
        __syncthreads();
        #pragma unroll
        for (int k = 0; k < 16; ++k) {
            int rl = wid * 16 + k;
            int s0 = seg[rl], s1 = seg[rl + 1];
            float a0 = 0.f, a1 = 0.f;
            for (int j = s0 + eh; j < s1; j += 2) {
                u64 p = rec2[j];
                int c = (int)((unsigned)p & 0xFFFFFF);
                float v = __uint_as_float((unsigned)(p >> 32));
                unsigned g = h2b[((size_t)(unsigned)c << 5) + up];
                a0 = fmaf(v, unlo(g), a0);
                a1 = fmaf(v, unhi(g), a1);
            }
            accA[k] += a0;
            accB[k] += a1;
        }
    }

    int node0 = (b << SB) + wid * 16;
    #pragma unroll
    for (int k = 0; k < 16; ++k) {
        int node = node0 + k;
        if (node < N) {
            float a0 = accA[k] + __shfl_xor(accA[k], 32);
            float a1 = accB[k] + __shfl_xor(accB[k], 32);
            if (eh == 0) {
                float di = dis[node];
                unsigned gs = h2b[((size_t)node << 5) + up];
                float2 bv = *(const float2*)(bias + 2 * up);
                float2 o;
                o.x = di * (a0 + FILL * unlo(gs)) + bv.x;
                o.y = di * (a1 + FILL * unhi(gs)) + bv.y;
                *(float2*)(out + ((size_t)node << 6) + 2 * up) = o;
            }
        }
    }
}

// ---------------- fallback (atomic scatter) ----------------

__global__ void k_fb_deg_init(float* __restrict__ deg, int n) {
    int i = blockIdx.x * blockDim.x + threadIdx.x;
    if (i < n) deg[i] = FILL;
}
__global__ void k_fb_deg_edges(const int* __restrict__ row, const float* __restrict__ w,
                               float* __restrict__ deg, int E) {
    int e = blockIdx.x * blockDim.x + threadIdx.x;
    if (e < E) atomicAdd(&deg[row[e]], w[e]);
}
__global__ void k_fb_dis(const float* __restrict__ deg, float* __restrict__ dis, int n) {
    int i = blockIdx.x * blockDim.x + threadIdx.x;
    if (i < n) {
        float d = deg[i];
        dis[i] = (d > 0.f) ? rsqrtf(fmaxf(d, 1e-12f)) : 0.f;
    }
}
__global__ void k_fb_outinit(const unsigned* __restrict__ h2b, const float* __restrict__ dis,
                             const float* __restrict__ bias, float* __restrict__ out, int n) {
    int t = blockIdx.x * blockDim.x + threadIdx.x;
    if (t < n * 64) {
        int i = t >> 6, u = t & 63;
        unsigned g = h2b[(size_t)i * 32 + (u >> 1)];
        float hv = (u & 1) ? unhi(g) : unlo(g);
        out[t] = FILL * dis[i] * hv + bias[u];
    }
}
__global__ __launch_bounds__(256) void k_fb_scatter(const int* __restrict__ row,
                                                    const int* __restrict__ col,
                                                    const float* __restrict__ w,
                                                    const float* __restrict__ dis,
                                                    const unsigned* __restrict__ h2b,
                                                    float* __restrict__ out, int E) {
    long long t = (long long)blockIdx.x * blockDim.x + threadIdx.x;
    int e = (int)(t >> 4);
    int j = (int)(t & 15);
    if (e < E) {
        int r = row[e], c = col[e];
        float nw = dis[r] * w[e];
        uint2 g2 = *(const uint2*)(h2b + (size_t)c * 32 + 2 * j);
        float* op = out + (long long)r * 64 + j * 4;
        atomicAdd(op + 0, unlo(g2.x) * nw);
        atomicAdd(op + 1, unhi(g2.x) * nw);
        atomicAdd(op + 2, unlo(g2.y) * nw);
        atomicAdd(op + 3, unhi(g2.y) * nw);
    }
}

// ---------------- launch ----------------

extern "C" void kernel_launch(void* const* d_in, const int* in_sizes, int n_in,
                              void* d_out, int out_size, void* d_ws, size_t ws_size,
                              hipStream_t stream) {
    const float* x    = (const float*)d_in[0];
    const int*   ei   = (const int*)d_in[1];
    const float* ew   = (const float*)d_in[2];
    const float* kern = (const float*)d_in[3];
    const float* bias = (const float*)d_in[4];
    float* out = (float*)d_out;

    int N = in_sizes[0] / 64;
    int E = in_sizes[1] / 2;
    const int* row = ei;
    const int* col = ei + E;

    const int B = 256;
    int NB = (N + BKN - 1) >> SB;     // buckets == gemm tiles

    size_t need = (size_t)E * 8               // eA
                + (size_t)N * 128             // h2b (bf16 pairs)
                + (size_t)N * 4               // dis
                + (size_t)(3 * NB + 1) * 4;   // bcnt, bstart[NB+1], bcur

    if (ws_size >= need && NB <= 2048 && N <= (1 << 24)) {
        char* p = (char*)d_ws;
        u64*      eA    = (u64*)p;         p += (size_t)E * 8;
        unsigned* h2b   = (unsigned*)p;    p += (size_t)N * 128;
        float*    dis   = (float*)p;       p += (size_t)N * 4;
        int*      bcnt  = (int*)p;         p += (size_t)NB * 4;
        int*      bstart= (int*)p;         p += (size_t)(NB + 1) * 4;
        int*      bcur  = (int*)p;

        int nt = (E + 4095) >> 12;
        hipMemsetAsync(bcnt, 0, (size_t)NB * 4, stream);
        k_bhist<<<256, B, 0, stream>>>(row, bcnt, E, NB);
        k_bscan<<<1, 1024, 0, stream>>>(bcnt, bstart, bcur, NB, E);
        k_bscatter<<<nt, B, 0, stream>>>(row, col, ew, bcur, eA, E, NB);
        k_gemm<<<NB, B, 0, stream>>>(x, kern, bstart, eA, dis, h2b, N);
        k_pull<<<NB, B, 0, stream>>>(bstart, eA, h2b, dis, bias, out, N);
    } else {
        char* p = (char*)d_ws;
        unsigned* h2b = (unsigned*)p;  p += (size_t)N * 128;
        float*    deg = (float*)p;     p += (size_t)N * 4;
        float*    dis = (float*)p;

        k_fb_deg_init<<<(N + B - 1) / B, B, 0, stream>>>(deg, N);
        k_fb_deg_edges<<<(E + B - 1) / B, B, 0, stream>>>(row, ew, deg, E);
        k_fb_dis<<<(N + B - 1) / B, B, 0, stream>>>(deg, dis, N);
        k_gemm<<<(N + 63) / 64, B, 0, stream>>>(x, kern, nullptr, nullptr, dis, h2b, N);
        k_fb_outinit<<<((long long)N * 64 + B - 1) / B, B, 0, stream>>>(h2b, dis, bias, out, N);
        long long st = (long long)E * 16;
        k_fb_scatter<<<(st + B - 1) / B, B, 0, stream>>>(row, col, ew, dis, h2b, out, E);
    }
}